// Round 8
// baseline (148.292 us; speedup 1.0000x reference)
//
#include <hip/hip_runtime.h>
#include <hip/hip_fp16.h>

// Problem constants (B,S,H,N_IN,N_PROC,R) = (4,1024,1024,64,16,128)
#define T_TOK 4096   // B*S tokens
#define H_DIM 1024
#define NIN   64
#define NP    16
#define R_DIM 128
#define S_DIM 1024
#define N1    (NP * R_DIM)   // 2048

typedef _Float16 half8  __attribute__((ext_vector_type(8)));
typedef _Float16 half4v __attribute__((ext_vector_type(4)));
typedef float    floatx16 __attribute__((ext_vector_type(16)));

typedef __attribute__((address_space(3))) unsigned char lds_u8_t;
typedef __attribute__((address_space(1))) unsigned char gbl_u8_t;

__device__ __forceinline__ void g2l16(const void* g, void* l) {
  __builtin_amdgcn_global_load_lds((const gbl_u8_t*)g, (lds_u8_t*)l, 16, 0, 0);
}

// ---------------- GEMM1: 256x256 tile, 8 waves, m201-style 4-phase K-loop ---
// R8 = resubmit of R7 (container failed twice = infra-level error, no kernel
// verdict; static audit found no hang/OOB: uniform barriers, bijective grid,
// in-bounds LDS/global indices, race-free dbuf handoff).
// Ledger (do not retry): R1 split-K atomics -20; R2 8w@128^2 ~0; R3 BN=64 -16;
// R4 256x128@2-barrier -10; R6 2-sub-phase graft @128^2 -8.5. Guide regime
// gate: phase scheduling pays ONLY at 256^2-class geometry (m201 vs m228d).
// This kernel: BM=BN=256 BK=64, 8 waves 2Mx4N, wave tile 128x64, acc[4][2],
// 32 MFMA/wave/K-step. LDS 128KB dynamic = dbuf x (A 32KB + B 32KB); each
// operand = two R0-style packed halves (64 rows x 256B, (x, x+64) row-pair
// pack, 16-chunk XOR swizzle -> R0's verified conflict-free read math).
// Phases (4 per K-tile): {12 ds_read_b128; stage A/B quarter of kt+1 (2
// g2l16); s_barrier; setprio(1); 8 MFMA (C-quadrant p,j x K64); setprio(0);
// [q3: vmcnt(0) - loads had ~1 tile flight]; s_barrier}. No sched_barrier
// (m141). Accumulation order (kt,h) identical to R0 -> bitwise-same C.
template <int K, int N>
__global__ __launch_bounds__(512, 2)
void gemm256(const _Float16* __restrict__ A, const _Float16* __restrict__ BT,
             const float* __restrict__ gv, _Float16* __restrict__ C) {
  constexpr int NK = K / 64;
  extern __shared__ __align__(16) _Float16 dlds[];  // 2 x (A 16384 + B 16384)

  const int tid = threadIdx.x, wave = tid >> 6, lane = tid & 63;
  const int id = blockIdx.x;
  const int xcd = id & 7, s = id >> 3;
  const int byi = (s >> 3) + 2 * xcd;          // 2 m-slabs per XCD
  const int bxi = s & 7;
  const int m0 = byi * 256, n0 = bxi * 256;
  const int wmr = wave >> 2;                   // wave m-row 0..1 (128 rows)
  const int wnc = wave & 3;                    // wave n-col 0..3 (64 cols)
  const int nb3 = wnc & 1;                     // B pack-half bit within 128
  const int rl = lane >> 4, ql = lane & 15;    // staging: 4 rows x 16 chunks
  const int r = lane & 31, kh = lane >> 5;

  // stage one quarter (8KB) of A or B for K-col k0 into dst buffer.
  // quarter q covers packed rows q*32 .. q*32+31 (call cc = q*8 + wave).
  auto stageAq = [&](int q, int k0, _Float16* dst) {
    const int cc = q * 8 + wave;               // 0..31
    const int pr = cc * 4 + rl;                // packed row 0..127
    const int hf = pr >> 6, lrow = pr & 63;    // half, row-in-half
    const int cl = ql ^ (lrow & 15);           // logical chunk this lane fetches
    const int mrow = hf * 128 + lrow + ((cl >> 3) << 6);
    g2l16(A + (size_t)(m0 + mrow) * K + k0 + (cl & 7) * 8, dst + cc * 512);
  };
  auto stageBq = [&](int q, int k0, _Float16* dst) {
    const int cc = q * 8 + wave;
    const int pr = cc * 4 + rl;
    const int hf = pr >> 6, lrow = pr & 63;
    const int cl = ql ^ (lrow & 15);
    const int nrow = hf * 128 + lrow + ((cl >> 3) << 6);
    g2l16(BT + (size_t)(n0 + nrow) * K + k0 + (cl & 7) * 8, dst + cc * 512);
  };

  floatx16 acc[4][2];
  #pragma unroll
  for (int g = 0; g < 4; ++g)
    #pragma unroll
    for (int j = 0; j < 2; ++j) acc[g][j] = (floatx16)0.f;

  // prologue: full tile 0 into buf0
  #pragma unroll
  for (int q = 0; q < 4; ++q) { stageAq(q, 0, dlds); stageBq(q, 0, dlds + 16384); }
  __builtin_amdgcn_s_waitcnt(0xF70);   // vmcnt(0)
  __builtin_amdgcn_s_barrier();

  for (int kt = 0; kt < NK; ++kt) {
    _Float16* cA = dlds + (kt & 1) * 32768;
    _Float16* cB = cA + 16384;
    _Float16* nA = dlds + ((kt + 1) & 1) * 32768;
    _Float16* nB = nA + 16384;
    const _Float16* Ah = cA + wmr * 8192;          // this wave's A-half
    const _Float16* Bh = cB + (wnc >> 1) * 8192;   // this wave's B-half
    #pragma unroll
    for (int q = 0; q < 4; ++q) {
      const int p = q & 1;       // A quadrant (rows p*64..p*64+63 of wave tile)
      const int j = q >> 1;      // B col group (j*32..j*32+31 of wave's 64)
      half8 af[2][4], bf[4];
      #pragma unroll
      for (int h = 0; h < 4; ++h) {
        const int pA = (2 * h + kh + (p << 3)) ^ (r & 15);
        af[0][h] = *reinterpret_cast<const half8*>(&Ah[(r) * 128 + pA * 8]);
        af[1][h] = *reinterpret_cast<const half8*>(&Ah[(32 + r) * 128 + pA * 8]);
        const int pB = (2 * h + kh + (nb3 << 3)) ^ (r & 15);
        bf[h] = *reinterpret_cast<const half8*>(&Bh[(j * 32 + r) * 128 + pB * 8]);
      }
      if (kt + 1 < NK) { stageAq(q, (kt + 1) * 64, nA); stageBq(q, (kt + 1) * 64, nB); }
      __builtin_amdgcn_s_barrier();
      __builtin_amdgcn_s_setprio(1);
      #pragma unroll
      for (int h = 0; h < 4; ++h) {
        acc[p * 2 + 0][j] = __builtin_amdgcn_mfma_f32_32x32x16_f16(af[0][h], bf[h], acc[p * 2 + 0][j], 0, 0, 0);
        acc[p * 2 + 1][j] = __builtin_amdgcn_mfma_f32_32x32x16_f16(af[1][h], bf[h], acc[p * 2 + 1][j], 0, 0, 0);
      }
      __builtin_amdgcn_s_setprio(0);
      if (q == 3 && kt + 1 < NK)
        __builtin_amdgcn_s_waitcnt(0xF70);   // vmcnt(0): kt+1 landed (1 tile flight)
      __builtin_amdgcn_s_barrier();
    }
  }

  // epilogue: gated f16 store. 32x32 C/D: col=lane&31, row=(reg&3)+8*(reg>>2)+4*kh
  const int neuron = bxi * 2 + (wnc >> 1);   // BN=256 spans 2 neurons
  #pragma unroll
  for (int g = 0; g < 4; ++g) {
    const int rbase = wmr * 128 + (g >> 1) * 64 + (g & 1) * 32;
    #pragma unroll
    for (int g4 = 0; g4 < 4; ++g4)
      #pragma unroll
      for (int rr = 0; rr < 4; ++rr) {
        const int rowL = rbase + rr + 8 * g4 + 4 * kh;
        const float gt = gv[(size_t)(m0 + rowL) * NP + neuron];  // L1-hot
        #pragma unroll
        for (int j = 0; j < 2; ++j)
          C[(size_t)(m0 + rowL) * N + n0 + wnc * 64 + j * 32 + r] =
              (_Float16)(acc[g][j][g4 * 4 + rr] * gt);
      }
  }
}

// ---------------- GEMM2: R0-exact 128x128 kernel (133.0us-verified) --------
template <int GATE, int K, int N>
__global__ __launch_bounds__(256)
void gemm_kernel(const _Float16* __restrict__ A, const _Float16* __restrict__ BT,
                 const float* __restrict__ gv, void* __restrict__ Cv) {
  constexpr int NK = K / 64;
  constexpr int GX = N / 128;
  __shared__ __align__(16) _Float16 smem[4][64 * 128];  // A0 A1 B0 B1

  const int tid = threadIdx.x, wave = tid >> 6, lane = tid & 63;
  const int id = blockIdx.x;
  const int xcd = id & 7, s = id >> 3;
  const int byi = s / GX + 4 * xcd;
  const int bxi = s % GX;
  const int m0 = byi * 128, n0 = bxi * 128;
  const int wr = (wave >> 1) * 64, wc = (wave & 1) * 64;
  const int rl = lane >> 4, ql = lane & 15;
  const int r = lane & 31, kh = lane >> 5;

  auto stage = [&](const _Float16* __restrict__ base, int off0, int k0,
                   _Float16* dst) {
    #pragma unroll
    for (int c = 0; c < 4; ++c) {
      const int cc = wave * 4 + c;
      const int lrow = cc * 4 + rl;
      const int cl = ql ^ (lrow & 15);
      const int row = lrow + ((cl >> 3) << 6);
      g2l16(base + (size_t)(off0 + row) * K + k0 + (cl & 7) * 8, dst + cc * 512);
    }
  };

  floatx16 acc[2][2];
  #pragma unroll
  for (int i = 0; i < 2; ++i)
    #pragma unroll
    for (int j = 0; j < 2; ++j) acc[i][j] = (floatx16)0.f;

  _Float16 *cA = smem[0], *nA = smem[1], *cB = smem[2], *nB = smem[3];
  stage(A, m0, 0, cA);
  stage(BT, n0, 0, cB);

  #pragma unroll 2
  for (int k = 0; k < NK; ++k) {
    if (k + 1 < NK) {
      stage(A, m0, (k + 1) * 64, nA);
      stage(BT, n0, (k + 1) * 64, nB);
      __builtin_amdgcn_s_waitcnt(0xF78);   // vmcnt(8)
    } else {
      __builtin_amdgcn_s_waitcnt(0xF70);   // vmcnt(0)
    }
    __builtin_amdgcn_s_barrier();
    __builtin_amdgcn_sched_barrier(0);
    #pragma unroll
    for (int h = 0; h < 4; ++h) {
      const int pA = (2 * h + kh + ((wave >> 1) << 3)) ^ (r & 15);
      const int pB = (2 * h + kh + ((wave & 1) << 3)) ^ (r & 15);
      half8 af[2], bf[2];
      #pragma unroll
      for (int i = 0; i < 2; ++i)
        af[i] = *reinterpret_cast<const half8*>(&cA[(i * 32 + r) * 128 + pA * 8]);
      #pragma unroll
      for (int j = 0; j < 2; ++j)
        bf[j] = *reinterpret_cast<const half8*>(&cB[(j * 32 + r) * 128 + pB * 8]);
      #pragma unroll
      for (int i = 0; i < 2; ++i)
        #pragma unroll
        for (int j = 0; j < 2; ++j)
          acc[i][j] = __builtin_amdgcn_mfma_f32_32x32x16_f16(af[i], bf[j], acc[i][j], 0, 0, 0);
    }
    __builtin_amdgcn_sched_barrier(0);
    __builtin_amdgcn_s_barrier();
    _Float16* t;
    t = cA; cA = nA; nA = t;
    t = cB; cB = nB; nB = t;
  }

  if (GATE) {
    _Float16* C = (_Float16*)Cv;
    #pragma unroll
    for (int i = 0; i < 2; ++i)
      #pragma unroll
      for (int g4 = 0; g4 < 4; ++g4)
        #pragma unroll
        for (int rr = 0; rr < 4; ++rr) {
          const int rowL = wr + i * 32 + rr + 8 * g4 + 4 * kh;
          const float g = gv[(size_t)(m0 + rowL) * NP + bxi];
          #pragma unroll
          for (int j = 0; j < 2; ++j)
            C[(size_t)(m0 + rowL) * N + n0 + wc + j * 32 + r] =
                (_Float16)(acc[i][j][g4 * 4 + rr] * g);
        }
  } else {
    float* C = (float*)Cv;
    #pragma unroll
    for (int i = 0; i < 2; ++i)
      #pragma unroll
      for (int g4 = 0; g4 < 4; ++g4)
        #pragma unroll
        for (int rr = 0; rr < 4; ++rr) {
          const int rowL = wr + i * 32 + rr + 8 * g4 + 4 * kh;
          #pragma unroll
          for (int j = 0; j < 2; ++j)
            C[(size_t)(m0 + rowL) * N + n0 + wc + j * 32 + r] = acc[i][j][g4 * 4 + rr];
        }
  }
}

// ---------------- prep: gates + cast + 2 transposes, ONE dispatch (R0) -----
__global__ __launch_bounds__(256)
void prep_kernel(const float* __restrict__ enr, const float* __restrict__ cw,
                 const float* __restrict__ cb, const float* __restrict__ inter,
                 const float* __restrict__ dproj, const float* __restrict__ uproj,
                 float* __restrict__ gates, _Float16* __restrict__ Xh,
                 _Float16* __restrict__ BT1, _Float16* __restrict__ UT) {
  __shared__ __align__(16) char smem[25664];
  const int tid = threadIdx.x;
  const int bx = blockIdx.x, nb = gridDim.x;
  {
    const float4* src = (const float4*)inter;
    half4v* dst = (half4v*)Xh;
    for (int i = bx * 256 + tid; i < T_TOK * H_DIM / 4; i += nb * 256) {
      float4 v = src[i];
      half4v o;
      o[0] = (_Float16)v.x; o[1] = (_Float16)v.y; o[2] = (_Float16)v.z; o[3] = (_Float16)v.w;
      dst[i] = o;
    }
  }
  if (bx < 256) {
    float (*sw)[321] = (float (*)[321])smem;
    float (*se)[NIN] = (float (*)[NIN])(smem + 20544);
    const int t0 = bx * 16;
    const int b = t0 >> 10, s0 = t0 & 1023;
    for (int i = tid; i < NP * 320; i += 256) sw[i / 320][i % 320] = cw[i];
    for (int i = tid; i < 20 * NIN; i += 256) {
      int rr = i >> 6, c = i & 63, s = s0 + rr - 2;
      se[rr][c] = (s >= 0 && s < S_DIM) ? enr[((size_t)b * S_DIM + s) * NIN + c] : 0.f;
    }
    __syncthreads();
    const int lt = tid >> 4, n = tid & 15;
    float acc = cb[n];
    #pragma unroll
    for (int dh = 0; dh < 5; ++dh) {
      const float* wrow = &sw[n][dh * 64];
      const float* erow = se[lt + dh];
      #pragma unroll
      for (int j = 0; j < NIN; ++j) acc += erow[j] * wrow[j];
    }
    gates[(size_t)(t0 + lt) * NP + n] = 1.f / (1.f + expf(-acc));
    __syncthreads();
  }
  for (int u = bx; u < 4096; u += nb) {
    const float* src; _Float16* dst; int rows, cols, bxt, byt;
    if (u < 2048) {
      int n = u >> 7, rem = u & 127;
      src = dproj + (size_t)n * H_DIM * R_DIM;
      dst = BT1 + (size_t)n * R_DIM * H_DIM;
      rows = H_DIM; cols = R_DIM; bxt = rem & 3; byt = rem >> 2;
    } else {
      int u2 = u - 2048;
      src = uproj; dst = UT; rows = N1; cols = H_DIM;
      bxt = u2 & 31; byt = u2 >> 5;
    }
    float (*tile)[33] = (float (*)[33])smem;
    const int c0 = bxt * 32, r0 = byt * 32;
    const int tx = tid & 31, ty = tid >> 5;
    #pragma unroll
    for (int k = 0; k < 32; k += 8)
      tile[ty + k][tx] = src[(size_t)(r0 + ty + k) * cols + c0 + tx];
    __syncthreads();
    #pragma unroll
    for (int k = 0; k < 32; k += 8)
      dst[(size_t)(c0 + ty + k) * rows + r0 + tx] = (_Float16)tile[tx][ty + k];
    __syncthreads();
  }
}

extern "C" void kernel_launch(void* const* d_in, const int* in_sizes, int n_in,
                              void* d_out, int out_size, void* d_ws, size_t ws_size,
                              hipStream_t stream) {
  const float* inter = (const float*)d_in[0];
  const float* enr   = (const float*)d_in[1];
  const float* convw = (const float*)d_in[2];
  const float* convb = (const float*)d_in[3];
  const float* dproj = (const float*)d_in[4];
  const float* uproj = (const float*)d_in[5];
  float* out   = (float*)d_out;
  float* gates = out + (size_t)T_TOK * H_DIM;

  _Float16* Xh  = (_Float16*)d_ws;
  _Float16* BT1 = Xh  + (size_t)T_TOK * H_DIM;
  _Float16* UT  = BT1 + (size_t)N1 * H_DIM;
  _Float16* Dsc = UT  + (size_t)H_DIM * N1;

  // opt-in to 128KB dynamic LDS (idempotent, capture-safe — R4 verified)
  hipFuncSetAttribute((const void*)gemm256<H_DIM, N1>,
                      hipFuncAttributeMaxDynamicSharedMemorySize, 131072);

  prep_kernel<<<8448, 256, 0, stream>>>(enr, convw, convb, inter, dproj, uproj,
                                        gates, Xh, BT1, UT);
  // GEMM1: 256x256 tiles, 4-phase schedule, grid 128, 8 waves
  gemm256<H_DIM, N1>
      <<<(T_TOK / 256) * (N1 / 256), 512, 131072, stream>>>(Xh, BT1, gates, Dsc);
  // GEMM2: R0-exact 128x128, grid 256
  gemm_kernel<0, N1, H_DIM>
      <<<(H_DIM / 128) * (T_TOK / 128), 256, 0, stream>>>(Dsc, UT, nullptr, (void*)out);
}